// Round 3
// baseline (296.566 us; speedup 1.0000x reference)
//
#include <hip/hip_runtime.h>
#include <math.h>
#include <limits.h>

// Problem constants (from reference): B=64, N=2048 predictions, M=64 gt boxes.
#define Bb 64
#define Nn 2048
#define Mm 64

// Exact cost expression shared by the cost-output tiles and the in-register
// hungarian scan. add/sub/abs/select only -> no contraction, bit-exact
// everywhere it is evaluated.
__device__ __forceinline__ float cost1(const float4 pb4, const float4 gb4,
                                       const float2 p2, const int g) {
    const float psv = (g == 0) ? p2.x : p2.y;
    float l1 = fabsf(pb4.x - gb4.x);
    l1 += fabsf(pb4.y - gb4.y);
    l1 += fabsf(pb4.z - gb4.z);
    l1 += fabsf(pb4.w - gb4.w);
    return (-psv) + l1;
}

// readlane lane 63 of an f64 (two b32 readlanes)
__device__ __forceinline__ double readlane_f64_63(double x) {
    const long long v = __double_as_longlong(x);
    const int lo = __builtin_amdgcn_readlane((int)v, 63);
    const int hi = __builtin_amdgcn_readlane((int)(v >> 32), 63);
    return __longlong_as_double(((long long)hi << 32) | (unsigned int)lo);
}

// readlane of an f64 from a dynamic (wave-uniform, SGPR) lane index
__device__ __forceinline__ double readlane_f64(double x, int sl) {
    const long long v = __double_as_longlong(x);
    const int lo = __builtin_amdgcn_readlane((int)v, sl);
    const int hi = __builtin_amdgcn_readlane((int)(v >> 32), sl);
    return __longlong_as_double(((long long)hi << 32) | (unsigned int)lo);
}

// ---------------------------------------------------------------------------
// Layout-A cost tile: out[b][j][i] (B,N,M), float4 stores. blk in [0, Bb*32).
// Takes the 256-thread virtual tid explicitly so two tiles can run inside one
// 512-thread block. Identical float expression to all prior rounds (absmax 0).
// ---------------------------------------------------------------------------
__device__ __forceinline__ void cost_tileA_t(
    int blk, int t, const float* __restrict__ ps, const float* __restrict__ pb,
    const int* __restrict__ gs, const float* __restrict__ gb,
    float* __restrict__ out)
{
    const int b  = blk >> 5;            // 32 tiles per batch
    const int j0 = (blk & 31) << 6;     // tile j start
    const int sub = t & 15;
    const int grp = t >> 4;             // 0..15

    const int i4 = sub << 2;
    const int4   g4 = ((const int4*)(gs + b * Mm))[sub];
    const float4 gbq0 = ((const float4*)gb)[b * Mm + i4 + 0];
    const float4 gbq1 = ((const float4*)gb)[b * Mm + i4 + 1];
    const float4 gbq2 = ((const float4*)gb)[b * Mm + i4 + 2];
    const float4 gbq3 = ((const float4*)gb)[b * Mm + i4 + 3];
    #pragma unroll
    for (int r = 0; r < 4; ++r) {
        const int j = j0 + grp + (r << 4);
        const float2 p2  = ((const float2*)ps)[b * Nn + j];
        const float4 pb4 = ((const float4*)pb)[b * Nn + j];
        float4 o;
        o.x = cost1(pb4, gbq0, p2, g4.x);
        o.y = cost1(pb4, gbq1, p2, g4.y);
        o.z = cost1(pb4, gbq2, p2, g4.z);
        o.w = cost1(pb4, gbq3, p2, g4.w);
        ((float4*)(out + (((size_t)b * Nn + j) << 6)))[sub] = o;
    }
}

// Value-only 64-lane f64 min via DPP; result lands in lane 63.
// Invalid source lanes receive +inf via update_dpp's `old` operand.
#define MIN_DPP(CTRL)                                                           \
  {                                                                             \
    const long long mb_ = __double_as_longlong(mv);                             \
    const int lo_ = __builtin_amdgcn_update_dpp(0, (int)mb_, CTRL, 0xf, 0xf, false);            \
    const int hi_ = __builtin_amdgcn_update_dpp(0x7ff00000, (int)(mb_ >> 32), CTRL, 0xf, 0xf, false); \
    const double om_ = __longlong_as_double(((long long)hi_ << 32) | (unsigned int)lo_);        \
    mv = fmin(mv, om_);                                                         \
  }

// Quad-permute lex-min compare-exchange on (fv, fj, fi0). After stages 0xB1
// ([1,0,3,2]) and 0x4E ([2,3,0,1]) every lane holds the min of its quad.
#define QUAD_MERGE(CTRL)                                                        \
  {                                                                             \
    const long long fb_ = __double_as_longlong(fv);                             \
    const int lo_ = __builtin_amdgcn_update_dpp(0, (int)fb_, CTRL, 0xf, 0xf, false);            \
    const int hi_ = __builtin_amdgcn_update_dpp(0, (int)(fb_ >> 32), CTRL, 0xf, 0xf, false);    \
    const int oj_ = __builtin_amdgcn_update_dpp(0, fj, CTRL, 0xf, 0xf, false);                  \
    const int oi_ = __builtin_amdgcn_update_dpp(0, fi0, CTRL, 0xf, 0xf, false);                 \
    const double ov_ = __longlong_as_double(((long long)hi_ << 32) | (unsigned int)lo_);        \
    if (ov_ < fv || (ov_ == fv && oj_ < fj)) { fv = ov_; fj = oj_; fi0 = oi_; } \
  }

// Barrier draining LDS ops only (lgkmcnt=0): vmcnt=63, expcnt=7, lgkmcnt=0.
__device__ __forceinline__ void barrier_lgkm() {
    asm volatile("" ::: "memory");
    __builtin_amdgcn_s_waitcnt(0xC07F);
    __builtin_amdgcn_s_barrier();
    asm volatile("" ::: "memory");
}

// Partial: candidate value/col AND pre-resolved owner row (0 = col free).
struct alignas(16) Pt { double v; int j; int i0; };

// v[j] lives at s_v[perm(j)]: owner-permuted so the row-end reload
// (vv[k] = s_v[(k<<9)+t]) hits bank (2t)&31 -> 2-way aliasing (free).
// 4 cols per thread now: col q = 4t+k  ->  s_v[((q&3)<<9) + (q>>2)].
__device__ __forceinline__ int vperm(int j) {          // j in [1, Nn]
    const int q = j - 1;
    return ((q & 3) << 9) + (q >> 2);
}

// ---------------------------------------------------------------------------
// Fused kernel, 512 threads/block (8 waves). Blocks [0,Bb) run the
// (buggy-JV) reference loop entirely from REGISTERS: thread t owns 4 columns
// (4t+1..4t+4); per-row gt data is broadcast via v_readlane. 8 waves
// (2/SIMD) so co-resident waves hide each other's DPP/f64/LDS latencies --
// at 4 waves (1/SIMD) the serial chain latency was fully exposed.
// Blocks [Bb, ...) each write TWO layout-A cost tiles (waves 0-3 / 4-7).
// ---------------------------------------------------------------------------
__global__ __launch_bounds__(512, 2) void hungarian_fused(
    const float* __restrict__ ps, const float* __restrict__ pb,
    const int* __restrict__ gs, const float* __restrict__ gb,
    float* __restrict__ out, float* __restrict__ out_row,
    float* __restrict__ out_col)
{
    const int bid = blockIdx.x;
    if (bid >= Bb) {                        // cost-output role: 2 tiles/block
        const int blk = ((bid - Bb) << 1) + (threadIdx.x >> 8);
        cost_tileA_t(blk, threadIdx.x & 255, ps, pb, gs, gb, out);
        return;
    }

    __shared__ double s_v[Nn];              // col potentials, PERMUTED layout
    __shared__ double s_delta[Mm + 8];      // delta per chain iteration
    __shared__ int    s_j[Mm + 8];          // col entered per chain iteration
    __shared__ Pt     s_part[2][8];         // per-wave partials (parity buf)
    __shared__ int    s_c4r[Mm];

    const int b = bid;
    const int t = threadIdx.x;              // 0..511
    const int lane = t & 63;
    const int wave = t >> 6;                // 0..7
    const double INF = __builtin_inf();

    for (int j = t; j < Nn; j += 512) s_v[j] = 0.0;

    // ---- per-thread column data: my 4 cols q = 4t..4t+3 (row-invariant) ----
    const float2* psb = (const float2*)(ps + (size_t)b * Nn * 2);
    const float4* pbb = (const float4*)(pb + (size_t)b * Nn * 4);
    float4 P[4]; float2 S[4];
    #pragma unroll
    for (int r = 0; r < 4; ++r) {
        P[r] = pbb[(t << 2) + r];
        S[r] = psb[(t << 2) + r];
    }
    // ---- per-lane gt data for row lane+1 (replicated in every wave) ----
    const float4 rgb = ((const float4*)gb)[b * Mm + lane];
    const int    rg  = gs[b * Mm + lane];

    __syncthreads();                        // s_v visible

    double vv[4];                       // scan copies of v for my 4 cols (4t+1+k)
    #pragma unroll
    for (int k = 0; k < 4; ++k) vv[k] = 0.0;
    double my_u = 0.0;                  // u[lane+1], replicated per wave
    int my_col = 0;                     // col assigned to row lane+1 (0 = none)
    int par = 0;

    for (int i = 1; i <= Mm; ++i) {
        int T = 0;
        int fjc = 0;                    // col entered this iteration (0 = virtual)
        int i0 = i;                     // row to scan
        int my_pos = -1;                // my row's position in this chain

        for (;;) {
            // ---- broadcast row i0's gt data + u[i0] via readlane (SALU) ----
            const int sl = __builtin_amdgcn_readfirstlane(i0) - 1;
            float4 gb4;
            gb4.x = __int_as_float(__builtin_amdgcn_readlane(__float_as_int(rgb.x), sl));
            gb4.y = __int_as_float(__builtin_amdgcn_readlane(__float_as_int(rgb.y), sl));
            gb4.z = __int_as_float(__builtin_amdgcn_readlane(__float_as_int(rgb.z), sl));
            gb4.w = __int_as_float(__builtin_amdgcn_readlane(__float_as_int(rgb.w), sl));
            const int g = __builtin_amdgcn_readlane(rg, sl);
            const double u0 = readlane_f64(my_u, sl);

            // bookkeeping overlaps the readlane/compute front-end
            if (t == 0) s_j[T] = fjc;
            if (fjc && ((fjc - 1) >> 2) == t) vv[(fjc - 1) & 3] = -INF; // mark used
            if (lane + 1 == i0) my_pos = T;

            // ---- recompute row costs in registers; f64 order matches ref ----
            double cur[4];
            #pragma unroll
            for (int k = 0; k < 4; ++k) {
                const float c = cost1(P[k], gb4, S[k], g);
                cur[k] = ((double)c - u0) - vv[k];
            }
            // in-thread tournament; strict < keeps left (lower j) on ties
            double v01 = cur[0]; int k01 = 0;
            if (cur[1] < v01) { v01 = cur[1]; k01 = 1; }
            double v23 = cur[2]; int k23 = 2;
            if (cur[3] < v23) { v23 = cur[3]; k23 = 3; }
            if (v23 < v01) { v01 = v23; k01 = k23; }
            double bv = v01;
            int bj = (t << 2) + 1 + k01;

            // ---- two-pass wave argmin: value-only f64 min, then first lane ----
            double mv = bv;
            MIN_DPP(0x111)   // row_shr:1
            MIN_DPP(0x112)   // row_shr:2
            MIN_DPP(0x114)   // row_shr:4
            MIN_DPP(0x118)   // row_shr:8
            MIN_DPP(0x142)   // row_bcast:15
            MIN_DPP(0x143)   // row_bcast:31
            const double wmin = readlane_f64_63(mv);
            const unsigned long long eq = __ballot(bv == wmin);
            const int l0 = (int)__builtin_ctzll(eq);   // lowest lane = lowest j
            const int bjw = __builtin_amdgcn_readlane(bj, l0);

            // Pre-barrier owner resolution for this wave's candidate.
            const unsigned long long mw = __ballot(my_col == bjw);
            const int i0w = mw ? (int)__builtin_ctzll(mw) + 1 : 0;
            if (lane == l0) {           // winner lane writes its exact f64 value
                Pt p; p.v = bv; p.j = bj; p.i0 = i0w;
                s_part[par][wave] = p;
            }
            barrier_lgkm();

            // ---- 8-partial merge: two LDS reads + lex-min, then quad-DPP ----
            const Pt pa = s_part[par][lane & 3];
            const Pt pc = s_part[par][4 + (lane & 3)];
            double fv; int fj; int fi0;
            if (pc.v < pa.v || (pc.v == pa.v && pc.j < pa.j)) {
                fv = pc.v; fj = pc.j; fi0 = pc.i0;
            } else {
                fv = pa.v; fj = pa.j; fi0 = pa.i0;
            }
            QUAD_MERGE(0xB1)   // quad_perm [1,0,3,2]
            QUAD_MERGE(0x4E)   // quad_perm [2,3,0,1]
            fjc = fj;
            if (t == 0) s_delta[T] = fv;
            T++; par ^= 1;

            if (fi0 == 0) break;                          // free col -> chain done
            i0 = fi0;                                     // owning row
        }

        barrier_lgkm();   // t0's s_delta/s_j visible to all waves
        // u[row at chain pos q] += delta_q ... delta_{T-1} (sequential = ref)
        if (my_pos >= 0) {
            double au = my_u;
            for (int k = my_pos; k < T; ++k) au += s_delta[k];
            my_u = au;
        }
        // v[col entered at pos q] -= delta_q ... (sequential = ref); skip j=0
        if (t < T) {
            const int jq = s_j[t];
            if (jq) {
                const int idx = vperm(jq);
                double nv = s_v[idx];
                for (int k = t; k < T; ++k) nv -= s_delta[k];
                s_v[idx] = nv;
            }
        }
        if (lane == i - 1) my_col = fjc;                 // augment (way==0)
        barrier_lgkm();   // s_v updates visible
        #pragma unroll
        for (int k = 0; k < 4; ++k) vv[k] = s_v[(k << 9) + t]; // un-mark (2-way banks)
    }

    // Emit row_ind (sorted pred idx) / col_ind (gt idx ordered by pred idx).
    if (t < Mm) s_c4r[t] = my_col - 1;   // wave 0: row t+1 -> 0-based pred idx
    __syncthreads();
    if (t < Mm) {
        const int my = s_c4r[t];
        int rank = 0;
        #pragma unroll 4
        for (int q = 0; q < Mm; ++q) rank += (s_c4r[q] < my);
        out_row[b * Mm + rank] = (float)my;
        out_col[b * Mm + rank] = (float)t;
    }
}

extern "C" void kernel_launch(void* const* d_in, const int* in_sizes, int n_in,
                              void* d_out, int out_size, void* d_ws, size_t ws_size,
                              hipStream_t stream) {
    const float* ps = (const float*)d_in[0];   // (64,2048,2) f32
    const float* pb = (const float*)d_in[1];   // (64,2048,4) f32
    const int*   gs = (const int*)d_in[2];     // (64,64) i32
    const float* gb = (const float*)d_in[3];   // (64,64,4) f32
    float* out = (float*)d_out;
    float* out_row = out + (size_t)Bb * Nn * Mm;          // 8388608
    float* out_col = out_row + Bb * Mm;                    // +4096

    (void)d_ws; (void)ws_size;
    // Single fused dispatch: 64 register-resident hungarian blocks (8 waves,
    // 4 cols/thread) + 1024 cost blocks (2 verified 64-j tiles each).
    hungarian_fused<<<Bb + Bb * (Nn / 128), 512, 0, stream>>>(
        ps, pb, gs, gb, out, out_row, out_col);
}

// Round 4
// 261.834 us; speedup vs baseline: 1.1326x; 1.1326x over previous
//
#include <hip/hip_runtime.h>
#include <math.h>
#include <limits.h>

// Problem constants (from reference): B=64, N=2048 predictions, M=64 gt boxes.
#define Bb 64
#define Nn 2048
#define Mm 64

// Exact cost expression shared by the cost-output tiles and the in-register
// hungarian scan. add/sub/abs/select only -> no contraction, bit-exact
// everywhere it is evaluated.
__device__ __forceinline__ float cost1(const float4 pb4, const float4 gb4,
                                       const float2 p2, const int g) {
    const float psv = (g == 0) ? p2.x : p2.y;
    float l1 = fabsf(pb4.x - gb4.x);
    l1 += fabsf(pb4.y - gb4.y);
    l1 += fabsf(pb4.z - gb4.z);
    l1 += fabsf(pb4.w - gb4.w);
    return (-psv) + l1;
}

// readlane lane 63 of an f64 (two b32 readlanes)
__device__ __forceinline__ double readlane_f64_63(double x) {
    const long long v = __double_as_longlong(x);
    const int lo = __builtin_amdgcn_readlane((int)v, 63);
    const int hi = __builtin_amdgcn_readlane((int)(v >> 32), 63);
    return __longlong_as_double(((long long)hi << 32) | (unsigned int)lo);
}

// readlane of an f64 from a dynamic (wave-uniform, SGPR) lane index
__device__ __forceinline__ double readlane_f64(double x, int sl) {
    const long long v = __double_as_longlong(x);
    const int lo = __builtin_amdgcn_readlane((int)v, sl);
    const int hi = __builtin_amdgcn_readlane((int)(v >> 32), sl);
    return __longlong_as_double(((long long)hi << 32) | (unsigned int)lo);
}

// ---------------------------------------------------------------------------
// Layout-A cost tile: out[b][j][i] (B,N,M), float4 stores. blk in [0, Bb*32).
// Takes the 256-thread virtual tid explicitly so two tiles can run inside one
// 512-thread block. Identical float expression to all prior rounds (absmax 0).
// ---------------------------------------------------------------------------
__device__ __forceinline__ void cost_tileA_t(
    int blk, int t, const float* __restrict__ ps, const float* __restrict__ pb,
    const int* __restrict__ gs, const float* __restrict__ gb,
    float* __restrict__ out)
{
    const int b  = blk >> 5;            // 32 tiles per batch
    const int j0 = (blk & 31) << 6;     // tile j start
    const int sub = t & 15;
    const int grp = t >> 4;             // 0..15

    const int i4 = sub << 2;
    const int4   g4 = ((const int4*)(gs + b * Mm))[sub];
    const float4 gbq0 = ((const float4*)gb)[b * Mm + i4 + 0];
    const float4 gbq1 = ((const float4*)gb)[b * Mm + i4 + 1];
    const float4 gbq2 = ((const float4*)gb)[b * Mm + i4 + 2];
    const float4 gbq3 = ((const float4*)gb)[b * Mm + i4 + 3];
    #pragma unroll
    for (int r = 0; r < 4; ++r) {
        const int j = j0 + grp + (r << 4);
        const float2 p2  = ((const float2*)ps)[b * Nn + j];
        const float4 pb4 = ((const float4*)pb)[b * Nn + j];
        float4 o;
        o.x = cost1(pb4, gbq0, p2, g4.x);
        o.y = cost1(pb4, gbq1, p2, g4.y);
        o.z = cost1(pb4, gbq2, p2, g4.z);
        o.w = cost1(pb4, gbq3, p2, g4.w);
        ((float4*)(out + (((size_t)b * Nn + j) << 6)))[sub] = o;
    }
}

// Value-only f64 min compare-exchange via DPP; works on variable `mv`.
// Invalid source lanes (if any) receive +inf via update_dpp's `old` operand.
#define MIN_DPP(CTRL)                                                           \
  {                                                                             \
    const long long mb_ = __double_as_longlong(mv);                             \
    const int lo_ = __builtin_amdgcn_update_dpp(0, (int)mb_, CTRL, 0xf, 0xf, false);            \
    const int hi_ = __builtin_amdgcn_update_dpp(0x7ff00000, (int)(mb_ >> 32), CTRL, 0xf, 0xf, false); \
    const double om_ = __longlong_as_double(((long long)hi_ << 32) | (unsigned int)lo_);        \
    mv = fmin(mv, om_);                                                         \
  }

// Barrier draining LDS ops only (lgkmcnt=0): vmcnt=63, expcnt=7, lgkmcnt=0.
__device__ __forceinline__ void barrier_lgkm() {
    asm volatile("" ::: "memory");
    __builtin_amdgcn_s_waitcnt(0xC07F);
    __builtin_amdgcn_s_barrier();
    asm volatile("" ::: "memory");
}

// Partial: candidate value/col AND pre-resolved owner row (0 = col free).
struct alignas(16) Pt { double v; int j; int i0; };

// v[j] lives at s_v[perm(j)]: owner-permuted so the row-end reload
// (vv[k] = s_v[(k<<9)+t]) hits bank (2t)&31 -> 2-way aliasing (free).
// 4 cols per thread: col q = 4t+k  ->  s_v[((q&3)<<9) + (q>>2)].
__device__ __forceinline__ int vperm(int j) {          // j in [1, Nn]
    const int q = j - 1;
    return ((q & 3) << 9) + (q >> 2);
}

// ---------------------------------------------------------------------------
// Fused kernel, 512 threads/block (8 waves). Blocks [0,Bb) run the
// (buggy-JV) reference loop entirely from REGISTERS: thread t owns 4 columns
// (4t+1..4t+4); per-row gt data is broadcast via v_readlane. Cross-wave
// merge: one ds_read_b128 of part[lane&7] + 3 value-only f64-min DPP stages
// (0xB1 / 0x4E / row_ror:4 -- valid since lanes 8..15 hold replicated
// copies), then ballot(pq.v==gmin): lowest set lane == lowest wave ==
// lowest column block, preserving the reference's lowest-j tie-break.
// Blocks [Bb, ...) each write TWO layout-A cost tiles (waves 0-3 / 4-7).
// ---------------------------------------------------------------------------
__global__ __launch_bounds__(512, 2) void hungarian_fused(
    const float* __restrict__ ps, const float* __restrict__ pb,
    const int* __restrict__ gs, const float* __restrict__ gb,
    float* __restrict__ out, float* __restrict__ out_row,
    float* __restrict__ out_col)
{
    const int bid = blockIdx.x;
    if (bid >= Bb) {                        // cost-output role: 2 tiles/block
        const int blk = ((bid - Bb) << 1) + (threadIdx.x >> 8);
        cost_tileA_t(blk, threadIdx.x & 255, ps, pb, gs, gb, out);
        return;
    }

    // Hungarian waves outrank any co-resident cost waves in issue arbitration.
    __builtin_amdgcn_s_setprio(1);

    __shared__ double s_v[Nn];              // col potentials, PERMUTED layout
    __shared__ double s_delta[Mm + 8];      // delta per chain iteration
    __shared__ int    s_j[Mm + 8];          // col entered per chain iteration
    __shared__ Pt     s_part[2][8];         // per-wave partials (parity buf)
    __shared__ int    s_c4r[Mm];

    const int b = bid;
    const int t = threadIdx.x;              // 0..511
    const int lane = t & 63;
    const int wave = t >> 6;                // 0..7
    const double INF = __builtin_inf();

    for (int j = t; j < Nn; j += 512) s_v[j] = 0.0;

    // ---- per-thread column data: my 4 cols q = 4t..4t+3 (row-invariant) ----
    const float2* psb = (const float2*)(ps + (size_t)b * Nn * 2);
    const float4* pbb = (const float4*)(pb + (size_t)b * Nn * 4);
    float4 P[4]; float2 S[4];
    #pragma unroll
    for (int r = 0; r < 4; ++r) {
        P[r] = pbb[(t << 2) + r];
        S[r] = psb[(t << 2) + r];
    }
    // ---- per-lane gt data for row lane+1 (replicated in every wave) ----
    const float4 rgb = ((const float4*)gb)[b * Mm + lane];
    const int    rg  = gs[b * Mm + lane];

    __syncthreads();                        // s_v visible

    double vv[4];                       // scan copies of v for my 4 cols (4t+1+k)
    #pragma unroll
    for (int k = 0; k < 4; ++k) vv[k] = 0.0;
    double my_u = 0.0;                  // u[lane+1], replicated per wave
    int my_col = 0;                     // col assigned to row lane+1 (0 = none)
    int par = 0;

    for (int i = 1; i <= Mm; ++i) {
        int T = 0;
        int fjc = 0;                    // col entered this iteration (0 = virtual)
        int i0 = i;                     // row to scan (always wave-uniform scalar)
        int my_pos = -1;                // my row's position in this chain

        for (;;) {
            // ---- broadcast row i0's gt data + u[i0] via readlane (SALU) ----
            const int sl = i0 - 1;      // uniform: loop var or readlane result
            float4 gb4;
            gb4.x = __int_as_float(__builtin_amdgcn_readlane(__float_as_int(rgb.x), sl));
            gb4.y = __int_as_float(__builtin_amdgcn_readlane(__float_as_int(rgb.y), sl));
            gb4.z = __int_as_float(__builtin_amdgcn_readlane(__float_as_int(rgb.z), sl));
            gb4.w = __int_as_float(__builtin_amdgcn_readlane(__float_as_int(rgb.w), sl));
            const int g = __builtin_amdgcn_readlane(rg, sl);
            const double u0 = readlane_f64(my_u, sl);

            // bookkeeping overlaps the readlane/compute front-end
            if (t == 0) s_j[T] = fjc;
            if (fjc && ((fjc - 1) >> 2) == t) vv[(fjc - 1) & 3] = -INF; // mark used
            if (lane + 1 == i0) my_pos = T;

            // ---- recompute row costs in registers; f64 order matches ref ----
            double cur[4];
            #pragma unroll
            for (int k = 0; k < 4; ++k) {
                const float c = cost1(P[k], gb4, S[k], g);
                cur[k] = ((double)c - u0) - vv[k];
            }
            // in-thread tournament; strict < keeps left (lower j) on ties
            double v01 = cur[0]; int k01 = 0;
            if (cur[1] < v01) { v01 = cur[1]; k01 = 1; }
            double v23 = cur[2]; int k23 = 2;
            if (cur[3] < v23) { v23 = cur[3]; k23 = 3; }
            if (v23 < v01) { v01 = v23; k01 = k23; }
            double bv = v01;
            int bj = (t << 2) + 1 + k01;

            // ---- two-pass wave argmin: value-only f64 min, then first lane ----
            double mv = bv;
            MIN_DPP(0x111)   // row_shr:1
            MIN_DPP(0x112)   // row_shr:2
            MIN_DPP(0x114)   // row_shr:4
            MIN_DPP(0x118)   // row_shr:8
            MIN_DPP(0x142)   // row_bcast:15
            MIN_DPP(0x143)   // row_bcast:31
            const double wmin = readlane_f64_63(mv);
            const unsigned long long eq = __ballot(bv == wmin);
            const int l0 = (int)__builtin_ctzll(eq);   // lowest lane = lowest j
            const int bjw = __builtin_amdgcn_readlane(bj, l0);

            // Pre-barrier owner resolution for this wave's candidate.
            const unsigned long long mw = __ballot(my_col == bjw);
            const int i0w = mw ? (int)__builtin_ctzll(mw) + 1 : 0;
            if (lane == l0) {           // winner lane writes its exact f64 value
                Pt p; p.v = bv; p.j = bj; p.i0 = i0w;
                s_part[par][wave] = p;
            }
            barrier_lgkm();

            // ---- cross-wave merge: 1 read + 3 value-min DPP + wave ballot ----
            const Pt pq = s_part[par][lane & 7];
            {
                double mv = pq.v;
                MIN_DPP(0xB1)    // quad_perm [1,0,3,2] : pair 1
                MIN_DPP(0x4E)    // quad_perm [2,3,0,1] : pair 2
                MIN_DPP(0x124)   // row_ror:4           : pair 4 (replicas OK)
                const double gv = mv;
                const unsigned long long wb = __ballot(pq.v == gv);
                const int wsel = (int)__builtin_ctzll(wb); // lowest wave idx
                fjc = __builtin_amdgcn_readlane(pq.j, wsel);
                const int fi0 = __builtin_amdgcn_readlane(pq.i0, wsel);
                if (t == 0) s_delta[T] = readlane_f64(pq.v, wsel);
                T++; par ^= 1;
                if (fi0 == 0) break;                      // free col -> chain done
                i0 = fi0;                                 // owning row (scalar)
            }
        }

        barrier_lgkm();   // t0's s_delta/s_j visible to all waves
        // u[row at chain pos q] += delta_q ... delta_{T-1} (sequential = ref)
        if (my_pos >= 0) {
            double au = my_u;
            for (int k = my_pos; k < T; ++k) au += s_delta[k];
            my_u = au;
        }
        // v[col entered at pos q] -= delta_q ... (sequential = ref); skip j=0
        if (t < T) {
            const int jq = s_j[t];
            if (jq) {
                const int idx = vperm(jq);
                double nv = s_v[idx];
                for (int k = t; k < T; ++k) nv -= s_delta[k];
                s_v[idx] = nv;
            }
        }
        if (lane == i - 1) my_col = fjc;                 // augment (way==0)
        barrier_lgkm();   // s_v updates visible
        #pragma unroll
        for (int k = 0; k < 4; ++k) vv[k] = s_v[(k << 9) + t]; // un-mark (2-way banks)
    }

    // Emit row_ind (sorted pred idx) / col_ind (gt idx ordered by pred idx).
    if (t < Mm) s_c4r[t] = my_col - 1;   // wave 0: row t+1 -> 0-based pred idx
    __syncthreads();
    if (t < Mm) {
        const int my = s_c4r[t];
        int rank = 0;
        #pragma unroll 4
        for (int q = 0; q < Mm; ++q) rank += (s_c4r[q] < my);
        out_row[b * Mm + rank] = (float)my;
        out_col[b * Mm + rank] = (float)t;
    }
}

extern "C" void kernel_launch(void* const* d_in, const int* in_sizes, int n_in,
                              void* d_out, int out_size, void* d_ws, size_t ws_size,
                              hipStream_t stream) {
    const float* ps = (const float*)d_in[0];   // (64,2048,2) f32
    const float* pb = (const float*)d_in[1];   // (64,2048,4) f32
    const int*   gs = (const int*)d_in[2];     // (64,64) i32
    const float* gb = (const float*)d_in[3];   // (64,64,4) f32
    float* out = (float*)d_out;
    float* out_row = out + (size_t)Bb * Nn * Mm;          // 8388608
    float* out_col = out_row + Bb * Mm;                    // +4096

    (void)d_ws; (void)ws_size;
    // Single fused dispatch: 64 register-resident hungarian blocks (8 waves,
    // 4 cols/thread) + 1024 cost blocks (2 verified 64-j tiles each).
    hungarian_fused<<<Bb + Bb * (Nn / 128), 512, 0, stream>>>(
        ps, pb, gs, gb, out, out_row, out_col);
}